// Round 13
// baseline (697.849 us; speedup 1.0000x reference)
//
#include <hip/hip_runtime.h>

#define LBL 64
#define TT 1024
#define BB 256
#define BOS 62
#define EOS 63
#define NEGV -10000.0f

typedef float v4f __attribute__((ext_vector_type(4)));

__device__ __forceinline__ float rl_f(float v, int l) {
    return __uint_as_float(__builtin_amdgcn_readlane(__float_as_uint(v), l));
}

// ONE WAVE per sentence, zero barriers. lane = next-label n.
// fv chain is REGISTER-ONLY (readlane broadcast, fmaxf trees) — r10's property.
// Index phase is DEFERRED one step (r12's property): its LDS gather issues at
// the top of step t+1, and the lgkmcnt wait lands after ~380 cyc of value-phase
// issue, so the gather latency is fully hidden. fvrow/tlds feed ONLY the
// deferred gather, never the fv recurrence.
__global__ __launch_bounds__(64, 1) void viterbi_kernel(
    const float* __restrict__ X, const float* __restrict__ trans,
    float* __restrict__ out)
{
    __shared__ __align__(16) float fvrow[2][LBL];    // fv history (gather only)
    __shared__ __align__(16) float tlds[LBL * LBL];  // [p][n] layout, 16 KiB
    __shared__ unsigned char bp[TT][LBL];            // 64 KiB backpointers
    __shared__ unsigned char path_s[TT];

    const int lane = threadIdx.x;            // next-label n
    const int b    = blockIdx.x;

    // tc[p] = T[p][n] in registers (compile-time indexed only)
    float tc[LBL];
#pragma unroll
    for (int p = 0; p < LBL; ++p) tc[p] = trans[p * LBL + lane];
    // LDS copy in [p][n] layout: gather addr = gs*2048 + k*256 + lane*4
    // -> bank = lane%32 (2 lanes/bank = free)
#pragma unroll
    for (int p = 0; p < LBL; ++p) tlds[p * LBL + lane] = tc[p];

    const float* Xb = X + (size_t)b * TT * LBL + lane;

    float fvv = (lane == BOS) ? 0.0f : NEGV;   // fv_{-1}
    // step 1 (par=1) gathers bp[0] from fv_{-1}: seed slot 1.
    fvrow[1][lane] = fvv;

    float dm = 0.0f; int dgs = 0;              // deferred (step t-1) state

    // deferred index completion for step tprev: recompute group dgs's 8 sums
    // from fvrow[par] (holds fv_{tprev-1}) — bitwise-identical f32 adds.
    auto DEFER = [&](int tprev, int par) {
        const float* fp = &fvrow[par][dgs << 3];
        const v4f fa = *(const v4f*)fp;              // <=2-way bank alias: free
        const v4f fb = *(const v4f*)(fp + 4);
        const float* tg = &tlds[(dgs << 3) * LBL + lane];
        float q0 = fa.x + tg[0 * LBL];
        float q1 = fa.y + tg[1 * LBL];
        float q2 = fa.z + tg[2 * LBL];
        float q3 = fa.w + tg[3 * LBL];
        float q4 = fb.x + tg[4 * LBL];
        float q5 = fb.y + tg[5 * LBL];
        float q6 = fb.z + tg[6 * LBL];
        float q7 = fb.w + tg[7 * LBL];
        int k = 7;
        k = (q6 == dm) ? 6 : k;
        k = (q5 == dm) ? 5 : k;
        k = (q4 == dm) ? 4 : k;
        k = (q3 == dm) ? 3 : k;
        k = (q2 == dm) ? 2 : k;
        k = (q1 == dm) ? 1 : k;
        k = (q0 == dm) ? 0 : k;                      // lowest k = first occ.
        bp[tprev][lane] = (unsigned char)((dgs << 3) | k);
    };

    auto STEP = [&](int t, float e, bool dodef) {
        const int par = t & 1;

        // (1) deferred gather + bp write for t-1 — reads issue here, the
        //     compiler's lgkmcnt wait lands after the value phase below
        if (dodef) DEFER(t - 1, par);

        // (2) value phase: m = max_p(fv[p]+T[p][n]); fv via readlane only
        float vg[8];
#pragma unroll
        for (int g = 0; g < 8; ++g) {
            float s0 = rl_f(fvv, 8*g+0) + tc[8*g+0];
            float s1 = rl_f(fvv, 8*g+1) + tc[8*g+1];
            float s2 = rl_f(fvv, 8*g+2) + tc[8*g+2];
            float s3 = rl_f(fvv, 8*g+3) + tc[8*g+3];
            float s4 = rl_f(fvv, 8*g+4) + tc[8*g+4];
            float s5 = rl_f(fvv, 8*g+5) + tc[8*g+5];
            float s6 = rl_f(fvv, 8*g+6) + tc[8*g+6];
            float s7 = rl_f(fvv, 8*g+7) + tc[8*g+7];
            vg[g] = fmaxf(fmaxf(fmaxf(s0, s1), fmaxf(s2, s3)),
                          fmaxf(fmaxf(s4, s5), fmaxf(s6, s7)));
        }
        const float m = fmaxf(fmaxf(fmaxf(vg[0], vg[1]), fmaxf(vg[2], vg[3])),
                              fmaxf(fmaxf(vg[4], vg[5]), fmaxf(vg[6], vg[7])));

        // (3) first group containing m (cndmask chain, lowest g wins)
        int gs = 7;
#pragma unroll
        for (int g = 6; g >= 0; --g) gs = (vg[g] == m) ? g : gs;

        // (4) hand to next step's deferred phase; (5) advance + publish
        dm = m; dgs = gs;
        fvv = m + e;                      // exact f32 add == numpy
        fvrow[par][lane] = fvv;           // after this step's gather reads
                                          // (same-wave DS FIFO order)
    };

    // emission double-window prefetch (no barriers -> loads never drained)
    float eC[8], eN[8];
#pragma unroll
    for (int j = 0; j < 8; ++j) eC[j] = Xb[(size_t)j * LBL];

    // peeled first window (t=0 has no deferred work)
#pragma unroll
    for (int j = 0; j < 8; ++j) eN[j] = Xb[(size_t)(8 + j) * LBL];
    STEP(0, eC[0], false);
#pragma unroll
    for (int j = 1; j < 8; ++j) STEP(j, eC[j], true);
#pragma unroll
    for (int j = 0; j < 8; ++j) eC[j] = eN[j];

    for (int base = 8; base < TT; base += 8) {
        if (base + 8 < TT) {                   // uniform scalar branch
#pragma unroll
            for (int j = 0; j < 8; ++j)
                eN[j] = Xb[(size_t)(base + 8 + j) * LBL];
        }
#pragma unroll
        for (int j = 0; j < 8; ++j) STEP(base + j, eC[j], true);
#pragma unroll
        for (int j = 0; j < 8; ++j) eC[j] = eN[j];
    }

    // epilogue: deferred index for t = TT-1; fv_{TT-2} sits in fvrow[TT&1=0]
    DEFER(TT - 1, 0);

    // ---- termination + wave argmax (butterfly, lower index wins ties) ----
    float bv = fvv + trans[lane * LBL + EOS];
    int   bi = lane;
#pragma unroll
    for (int d = 1; d < 64; d <<= 1) {
        float ov = __shfl_xor(bv, d, 64);
        int   oi = __shfl_xor(bi, d, 64);
        if (ov > bv || (ov == bv && oi < bi)) { bv = ov; bi = oi; }
    }
    if (lane == 0) out[b] = bv;

    // ---- backtrack: prefetch bp rows, chase via readlane (r5-validated) ----
    int stag = bi;   // wave-uniform
    unsigned char r0 = bp[TT-1][lane];
    unsigned char r1 = bp[TT-2][lane];
    unsigned char r2 = bp[TT-3][lane];
    unsigned char r3 = bp[TT-4][lane];
    for (int t4 = TT - 1; t4 >= 3; t4 -= 4) {
        int q0 = t4-4, q1 = t4-5, q2 = t4-6, q3 = t4-7;
        if (q0 < 0) q0 = 0;  if (q1 < 0) q1 = 0;
        if (q2 < 0) q2 = 0;  if (q3 < 0) q3 = 0;
        unsigned char m0 = bp[q0][lane];
        unsigned char m1 = bp[q1][lane];
        unsigned char m2 = bp[q2][lane];
        unsigned char m3 = bp[q3][lane];
        if (lane == ((t4-0) & 63)) path_s[t4-0] = (unsigned char)stag;
        stag = __builtin_amdgcn_readlane((int)r0, stag);
        if (lane == ((t4-1) & 63)) path_s[t4-1] = (unsigned char)stag;
        stag = __builtin_amdgcn_readlane((int)r1, stag);
        if (lane == ((t4-2) & 63)) path_s[t4-2] = (unsigned char)stag;
        stag = __builtin_amdgcn_readlane((int)r2, stag);
        if (lane == ((t4-3) & 63)) path_s[t4-3] = (unsigned char)stag;
        stag = __builtin_amdgcn_readlane((int)r3, stag);
        r0 = m0; r1 = m1; r2 = m2; r3 = m3;
    }

    // coalesced float path write (single wave, LDS program order)
    float* po = out + BB + (size_t)b * TT;
#pragma unroll
    for (int i = 0; i < TT / LBL; ++i)
        po[i * LBL + lane] = (float)path_s[i * LBL + lane];
}

extern "C" void kernel_launch(void* const* d_in, const int* in_sizes, int n_in,
                              void* d_out, int out_size, void* d_ws, size_t ws_size,
                              hipStream_t stream)
{
    const float* X     = (const float*)d_in[0];   // [256, 1024, 64]
    const float* trans = (const float*)d_in[1];   // [64, 64]
    float* out = (float*)d_out;                   // [256] scores ++ [256*1024] path

    viterbi_kernel<<<dim3(BB), dim3(64), 0, stream>>>(X, trans, out);
}

// Round 14
// 386.084 us; speedup vs baseline: 1.8075x; 1.8075x over previous
//
#include <hip/hip_runtime.h>

#define LBL 64
#define TT 1024
#define BB 256
#define BOS 62
#define EOS 63
#define NEGV -10000.0f

typedef float v2f __attribute__((ext_vector_type(2)));
typedef float v4f __attribute__((ext_vector_type(4)));

// ONE WAVE per sentence, zero barriers. lane = next-label n.
// Value phase: LDS-broadcast fv + packed pk_add/pk_max (lowest measured issue,
// r12: ~490 busy-cyc/step). Index phase: deferred one step; its 10 gather
// reads are issued at the TOP of the next step, ahead of the 16 value reads,
// so the value tree's FIFO lgkm waits drain them for free and the consume at
// step end waits ~0. sched_barrier(0) fences pin load->tree->consume order
// (r13's failure: compiler put the wait at the top).
__global__ __launch_bounds__(64, 1) void viterbi_kernel(
    const float* __restrict__ X, const float* __restrict__ trans,
    float* __restrict__ out)
{
    __shared__ __align__(16) float fvrow[2][LBL];    // fv history (dbuf)
    __shared__ __align__(16) float tlds[LBL * LBL];  // [p][n] layout, 16 KiB
    __shared__ unsigned char bp[TT][LBL];            // 64 KiB backpointers
    __shared__ unsigned char path_s[TT];

    const int lane = threadIdx.x;            // next-label n
    const int b    = blockIdx.x;

    // tc2[i] = {T[2i][n], T[2i+1][n]} packed register pairs (64 VGPR)
    v2f tc2[32];
#pragma unroll
    for (int i = 0; i < 32; ++i) {
        tc2[i][0] = trans[(2*i)   * LBL + lane];
        tc2[i][1] = trans[(2*i+1) * LBL + lane];
    }
    // gather table, [p][n]: addr = p*256B + lane*4 -> bank=lane%32, conflict-free
#pragma unroll
    for (int i = 0; i < 32; ++i) {
        tlds[(2*i)   * LBL + lane] = tc2[i][0];
        tlds[(2*i+1) * LBL + lane] = tc2[i][1];
    }

    const float* Xb = X + (size_t)b * TT * LBL + lane;

    float fvv = (lane == BOS) ? 0.0f : NEGV;   // fv_{-1}
    fvrow[1][lane] = fvv;                      // step0 value phase + step1 gather

    float dm = 0.0f; int dgs = 0;              // deferred (step t-1) state

    auto STEP = [&](int t, float e, bool dodef) {
        const int par = t & 1;
        // fvrow[par^1] holds fv_{t-1} (value phase); fvrow[par] holds fv_{t-2}
        // (gather target) and is overwritten with fv_t at step end.

        // ---- (1) deferred gather loads: issued FIRST (FIFO-ahead of value) ----
        v4f ga = {}, gb = {};
        float tq0=0,tq1=0,tq2=0,tq3=0,tq4=0,tq5=0,tq6=0,tq7=0;
        if (dodef) {
            const float* fp = &fvrow[par][dgs << 3];
            ga = *(const v4f*)fp;                    // broadcast b128 (free)
            gb = *(const v4f*)(fp + 4);
            const float* tg = &tlds[(dgs << 3) * LBL + lane];
            tq0 = tg[0 * LBL];  tq1 = tg[1 * LBL];   // 8x b32, conflict-free
            tq2 = tg[2 * LBL];  tq3 = tg[3 * LBL];
            tq4 = tg[4 * LBL];  tq5 = tg[5 * LBL];
            tq6 = tg[6 * LBL];  tq7 = tg[7 * LBL];
        }
        __builtin_amdgcn_sched_barrier(0);           // pin loads at step top

        // ---- (2) value phase: m = max_p(fv_{t-1}[p] + T[p][n]) ----
        const v4f* fr = (const v4f*)fvrow[par ^ 1];
        float vgs[8];
#pragma unroll
        for (int g = 0; g < 8; ++g) {
            const v4f fa = fr[2*g];                  // broadcast b128 reads
            const v4f fb = fr[2*g + 1];
            v2f s0 = __builtin_shufflevector(fa, fa, 0, 1) + tc2[4*g+0];
            v2f s1 = __builtin_shufflevector(fa, fa, 2, 3) + tc2[4*g+1];
            v2f s2 = __builtin_shufflevector(fb, fb, 0, 1) + tc2[4*g+2];
            v2f s3 = __builtin_shufflevector(fb, fb, 2, 3) + tc2[4*g+3];
            v2f w0 = __builtin_elementwise_max(s0, s1);   // v_pk_max_f32
            v2f w1 = __builtin_elementwise_max(s2, s3);
            v2f w  = __builtin_elementwise_max(w0, w1);
            vgs[g] = fmaxf(w[0], w[1]);              // exact group max
        }
        const float m =
            fmaxf(fmaxf(fmaxf(vgs[0], vgs[1]), fmaxf(vgs[2], vgs[3])),
                  fmaxf(fmaxf(vgs[4], vgs[5]), fmaxf(vgs[6], vgs[7])));
        int gs = 7;                                  // first group == m
#pragma unroll
        for (int g = 6; g >= 0; --g) gs = (vgs[g] == m) ? g : gs;

        __builtin_amdgcn_sched_barrier(0);           // consume stays BELOW tree

        // ---- (3) consume gather: bp for step t-1 (lgkm already drained) ----
        if (dodef) {
            float q0 = ga.x + tq0;   // same f32 adds as value phase ->
            float q1 = ga.y + tq1;   //  bitwise equal -> exact np.argmax
            float q2 = ga.z + tq2;
            float q3 = ga.w + tq3;
            float q4 = gb.x + tq4;
            float q5 = gb.y + tq5;
            float q6 = gb.z + tq6;
            float q7 = gb.w + tq7;
            int k = 7;
            k = (q6 == dm) ? 6 : k;
            k = (q5 == dm) ? 5 : k;
            k = (q4 == dm) ? 4 : k;
            k = (q3 == dm) ? 3 : k;
            k = (q2 == dm) ? 2 : k;
            k = (q1 == dm) ? 1 : k;
            k = (q0 == dm) ? 0 : k;                  // lowest k = first occ.
            bp[t - 1][lane] = (unsigned char)((dgs << 3) | k);
        }

        // ---- (4) advance + publish (after this step's gather reads: FIFO) ----
        dm = m; dgs = gs;
        fvv = m + e;                      // exact f32 add == numpy
        fvrow[par][lane] = fvv;
    };

    // emission double-window prefetch (no barriers -> loads never drained)
    float eC[8], eN[8];
#pragma unroll
    for (int j = 0; j < 8; ++j) eC[j] = Xb[(size_t)j * LBL];

#pragma unroll
    for (int j = 0; j < 8; ++j) eN[j] = Xb[(size_t)(8 + j) * LBL];
    STEP(0, eC[0], false);
#pragma unroll
    for (int j = 1; j < 8; ++j) STEP(j, eC[j], true);
#pragma unroll
    for (int j = 0; j < 8; ++j) eC[j] = eN[j];

    for (int base = 8; base < TT; base += 8) {
        if (base + 8 < TT) {                   // uniform scalar branch
#pragma unroll
            for (int j = 0; j < 8; ++j)
                eN[j] = Xb[(size_t)(base + 8 + j) * LBL];
        }
#pragma unroll
        for (int j = 0; j < 8; ++j) STEP(base + j, eC[j], true);
#pragma unroll
        for (int j = 0; j < 8; ++j) eC[j] = eN[j];
    }

    // epilogue: deferred index for t = TT-1; fv_{TT-2} sits in fvrow[0]
    {
        const float* fp = &fvrow[0][dgs << 3];
        const v4f fa = *(const v4f*)fp;
        const v4f fb = *(const v4f*)(fp + 4);
        const float* tg = &tlds[(dgs << 3) * LBL + lane];
        float q0 = fa.x + tg[0 * LBL];
        float q1 = fa.y + tg[1 * LBL];
        float q2 = fa.z + tg[2 * LBL];
        float q3 = fa.w + tg[3 * LBL];
        float q4 = fb.x + tg[4 * LBL];
        float q5 = fb.y + tg[5 * LBL];
        float q6 = fb.z + tg[6 * LBL];
        float q7 = fb.w + tg[7 * LBL];
        int k = 7;
        k = (q6 == dm) ? 6 : k;
        k = (q5 == dm) ? 5 : k;
        k = (q4 == dm) ? 4 : k;
        k = (q3 == dm) ? 3 : k;
        k = (q2 == dm) ? 2 : k;
        k = (q1 == dm) ? 1 : k;
        k = (q0 == dm) ? 0 : k;
        bp[TT - 1][lane] = (unsigned char)((dgs << 3) | k);
    }

    // ---- termination + wave argmax (butterfly, lower index wins ties) ----
    float bv = fvv + trans[lane * LBL + EOS];
    int   bi = lane;
#pragma unroll
    for (int d = 1; d < 64; d <<= 1) {
        float ov = __shfl_xor(bv, d, 64);
        int   oi = __shfl_xor(bi, d, 64);
        if (ov > bv || (ov == bv && oi < bi)) { bv = ov; bi = oi; }
    }
    if (lane == 0) out[b] = bv;

    // ---- backtrack: prefetch bp rows, chase via readlane (r5-validated) ----
    int stag = bi;   // wave-uniform
    unsigned char r0 = bp[TT-1][lane];
    unsigned char r1 = bp[TT-2][lane];
    unsigned char r2 = bp[TT-3][lane];
    unsigned char r3 = bp[TT-4][lane];
    for (int t4 = TT - 1; t4 >= 3; t4 -= 4) {
        int q0 = t4-4, q1 = t4-5, q2 = t4-6, q3 = t4-7;
        if (q0 < 0) q0 = 0;  if (q1 < 0) q1 = 0;
        if (q2 < 0) q2 = 0;  if (q3 < 0) q3 = 0;
        unsigned char m0 = bp[q0][lane];
        unsigned char m1 = bp[q1][lane];
        unsigned char m2 = bp[q2][lane];
        unsigned char m3 = bp[q3][lane];
        if (lane == ((t4-0) & 63)) path_s[t4-0] = (unsigned char)stag;
        stag = __builtin_amdgcn_readlane((int)r0, stag);
        if (lane == ((t4-1) & 63)) path_s[t4-1] = (unsigned char)stag;
        stag = __builtin_amdgcn_readlane((int)r1, stag);
        if (lane == ((t4-2) & 63)) path_s[t4-2] = (unsigned char)stag;
        stag = __builtin_amdgcn_readlane((int)r2, stag);
        if (lane == ((t4-3) & 63)) path_s[t4-3] = (unsigned char)stag;
        stag = __builtin_amdgcn_readlane((int)r3, stag);
        r0 = m0; r1 = m1; r2 = m2; r3 = m3;
    }

    // coalesced float path write (single wave, LDS program order)
    float* po = out + BB + (size_t)b * TT;
#pragma unroll
    for (int i = 0; i < TT / LBL; ++i)
        po[i * LBL + lane] = (float)path_s[i * LBL + lane];
}

extern "C" void kernel_launch(void* const* d_in, const int* in_sizes, int n_in,
                              void* d_out, int out_size, void* d_ws, size_t ws_size,
                              hipStream_t stream)
{
    const float* X     = (const float*)d_in[0];   // [256, 1024, 64]
    const float* trans = (const float*)d_in[1];   // [64, 64]
    float* out = (float*)d_out;                   // [256] scores ++ [256*1024] path

    viterbi_kernel<<<dim3(BB), dim3(64), 0, stream>>>(X, trans, out);
}